// Round 12
// baseline (308.299 us; speedup 1.0000x reference)
//
#include <hip/hip_runtime.h>
#include <cstdint>
#include <math.h>

#define Nn   16
#define Cc   64
#define Ww   512
#define Hh   512
#define RED  64
#define OUTW 128

// Native vector type accepted by __builtin_nontemporal_load/store
typedef float fx4 __attribute__((ext_vector_type(4)));

// ---------------------------------------------------------------------------
// Kernel 1: pooled[n][w] = max over (c,h) of x[n][c][w][h]
// Block b = (n, w-quad): 4 waves, wave r owns row w = q*4+r (2KB/row/c).
// Depth-2 software pipeline; 8 independent accumulators; one butterfly at the
// end. NT loads (read-once 1GB stream, x is 4x L3). [R10 best]
// ---------------------------------------------------------------------------
__global__ void __launch_bounds__(256) pool_kernel(const float* __restrict__ x,
                                                   float* __restrict__ pooled) {
    const int b = blockIdx.x;            // n*128 + q
    const int n = b >> 7;
    const int q = b & 127;
    const int r = threadIdx.x >> 6;
    const int lane = threadIdx.x & 63;
    const int w = q * 4 + r;
    const float* base = x + ((size_t)n * Cc * Ww + w) * Hh + lane * 8;
    const size_t cstride = (size_t)Ww * Hh;

    float m0 = -INFINITY, m1 = -INFINITY, m2 = -INFINITY, m3 = -INFINITY;
    float m4 = -INFINITY, m5 = -INFINITY, m6 = -INFINITY, m7 = -INFINITY;

    fx4 a0 = __builtin_nontemporal_load(reinterpret_cast<const fx4*>(base));
    fx4 a1 = __builtin_nontemporal_load(reinterpret_cast<const fx4*>(base + 4));
    fx4 b0 = __builtin_nontemporal_load(reinterpret_cast<const fx4*>(base + cstride));
    fx4 b1 = __builtin_nontemporal_load(reinterpret_cast<const fx4*>(base + cstride + 4));

    #pragma unroll 8
    for (int c = 0; c < Cc - 2; c += 2) {
        const float* p2 = base + (size_t)(c + 2) * cstride;
        const float* p3 = base + (size_t)(c + 3) * cstride;
        const fx4 n0 = __builtin_nontemporal_load(reinterpret_cast<const fx4*>(p2));
        const fx4 n1 = __builtin_nontemporal_load(reinterpret_cast<const fx4*>(p2 + 4));
        const fx4 n2 = __builtin_nontemporal_load(reinterpret_cast<const fx4*>(p3));
        const fx4 n3 = __builtin_nontemporal_load(reinterpret_cast<const fx4*>(p3 + 4));
        m0 = fmaxf(m0, a0.x); m1 = fmaxf(m1, a0.y);
        m2 = fmaxf(m2, a0.z); m3 = fmaxf(m3, a0.w);
        m4 = fmaxf(m4, a1.x); m5 = fmaxf(m5, a1.y);
        m6 = fmaxf(m6, a1.z); m7 = fmaxf(m7, a1.w);
        m0 = fmaxf(m0, b0.x); m1 = fmaxf(m1, b0.y);
        m2 = fmaxf(m2, b0.z); m3 = fmaxf(m3, b0.w);
        m4 = fmaxf(m4, b1.x); m5 = fmaxf(m5, b1.y);
        m6 = fmaxf(m6, b1.z); m7 = fmaxf(m7, b1.w);
        a0 = n0; a1 = n1; b0 = n2; b1 = n3;
    }
    m0 = fmaxf(m0, a0.x); m1 = fmaxf(m1, a0.y);
    m2 = fmaxf(m2, a0.z); m3 = fmaxf(m3, a0.w);
    m4 = fmaxf(m4, a1.x); m5 = fmaxf(m5, a1.y);
    m6 = fmaxf(m6, a1.z); m7 = fmaxf(m7, a1.w);
    m0 = fmaxf(m0, b0.x); m1 = fmaxf(m1, b0.y);
    m2 = fmaxf(m2, b0.z); m3 = fmaxf(m3, b0.w);
    m4 = fmaxf(m4, b1.x); m5 = fmaxf(m5, b1.y);
    m6 = fmaxf(m6, b1.z); m7 = fmaxf(m7, b1.w);

    float m = fmaxf(fmaxf(fmaxf(m0, m1), fmaxf(m2, m3)),
                    fmaxf(fmaxf(m4, m5), fmaxf(m6, m7)));
    #pragma unroll
    for (int off = 1; off < 64; off <<= 1)
        m = fmaxf(m, __shfl_xor(m, off, 64));
    if (lane == 0) pooled[n * Ww + w] = m;
}

// ---------------------------------------------------------------------------
// Kernel 2a: h = pooled @ w1.T + b1, BatchNorm(batch stats) + ReLU. (R4)
// ---------------------------------------------------------------------------
__global__ void __launch_bounds__(256) mlp_h_kernel(
    const float* __restrict__ pooled,   // [16][512]
    const float* __restrict__ w1,       // [64][512]
    const float* __restrict__ b1,
    const float* __restrict__ gamma,
    const float* __restrict__ beta,
    float* __restrict__ hbn)            // [64][16]
{
    const int r = blockIdx.x;
    const int t = threadIdx.x;
    const int n = t & 15;
    const int slice = t >> 4;
    const float4* w1r = reinterpret_cast<const float4*>(w1 + r * Ww + slice * 32);
    const float4* pn  = reinterpret_cast<const float4*>(pooled + n * Ww + slice * 32);

    float acc = 0.f;
    #pragma unroll
    for (int j = 0; j < 8; ++j) {
        const float4 a = w1r[j];
        const float4 p = pn[j];
        acc += a.x * p.x + a.y * p.y + a.z * p.z + a.w * p.w;
    }
    __shared__ float part[16][17];
    part[slice][n] = acc;
    __syncthreads();
    if (t < 16) {                        // t == n
        float h = b1[r];
        #pragma unroll
        for (int s = 0; s < 16; ++s) h += part[s][t];
        float sum = h, sq = h * h;
        #pragma unroll
        for (int off = 1; off < 16; off <<= 1) {
            sum += __shfl_xor(sum, off, 64);
            sq  += __shfl_xor(sq,  off, 64);
        }
        const float mu  = sum * (1.f / 16.f);
        const float var = sq  * (1.f / 16.f) - mu * mu;
        const float is  = 1.f / sqrtf(var + 1e-5f);
        const float v   = gamma[r] * (h - mu) * is + beta[r];
        hbn[r * Nn + t] = fmaxf(v, 0.f);
    }
}

// ---------------------------------------------------------------------------
// Kernel 2b: logits + rank-based top-128 (softmax monotone, skipped). (R4)
// Tie-break matches jax.lax.top_k (value desc, index asc); rank-select emits
// indices already sorted ascending.
// ---------------------------------------------------------------------------
__global__ void __launch_bounds__(512) logits_topk_kernel(
    const float* __restrict__ hbn,      // [64][16]
    const float* __restrict__ w2,       // [512][64]
    const float* __restrict__ b2,
    int* __restrict__ idx_out)          // [16][128]
{
    const int row = blockIdx.x;
    const int w = threadIdx.x;

    __shared__ float hrow[RED];
    __shared__ float logits_row[Ww];
    __shared__ unsigned long long sel_mask[Ww / 64];

    float4 wv[16];
    const float4* w2r = reinterpret_cast<const float4*>(w2 + w * RED);
    #pragma unroll
    for (int j = 0; j < 16; ++j) wv[j] = w2r[j];
    if (w < RED) hrow[w] = hbn[w * Nn + row];
    __syncthreads();

    float acc = b2[w];
    #pragma unroll
    for (int j = 0; j < 16; ++j) {
        acc += wv[j].x * hrow[j * 4]     + wv[j].y * hrow[j * 4 + 1]
             + wv[j].z * hrow[j * 4 + 2] + wv[j].w * hrow[j * 4 + 3];
    }
    logits_row[w] = acc;
    __syncthreads();

    const float v = logits_row[w];
    int rank = 0;
    for (int ww = 0; ww < Ww; ++ww) {
        const float u = logits_row[ww];
        rank += (u > v || (u == v && ww < w)) ? 1 : 0;
    }
    const bool sel = (rank < OUTW);
    const unsigned long long m = __ballot(sel);
    if ((w & 63) == 0) sel_mask[w >> 6] = m;
    __syncthreads();
    if (sel) {
        int pos = 0;
        #pragma unroll
        for (int bb = 0; bb < (Ww / 64); ++bb)
            if (bb < (w >> 6)) pos += __popcll(sel_mask[bb]);
        pos += __popcll(sel_mask[w >> 6] & ((1ULL << (w & 63)) - 1ULL));
        idx_out[row * OUTW + pos] = w;
    }
}

// ---------------------------------------------------------------------------
// Kernel 3: gather (R10 + c-rotation). Block b=(n,c,half): 64 sorted rows
// from one 1MB plane into a contiguous 128KB write slab, NT load+store.
// NEW: row-processing order rotated by rot=(c*21)&63 so the 64 c-blocks of a
// given n do NOT read the same 2KB offset at 1MB stride simultaneously
// (HBM channel de-aliasing). Same exact read/write set -> bitwise-identical.
// ---------------------------------------------------------------------------
__global__ void __launch_bounds__(256) gather_kernel(const float* __restrict__ x,
                                                     const int* __restrict__ idx,
                                                     float* __restrict__ out) {
    const int b = blockIdx.x;                 // (n*64 + c)*2 + half
    const int half = b & 1;
    const int nc = b >> 1;                    // n*64 + c
    const int n = nc >> 6;
    const int c = nc & 63;
    const int rot = (c * 21) & 63;            // de-phase c-blocks
    const int tid = threadIdx.x;
    __shared__ int sidx[64];
    if (tid < 64) sidx[tid] = idx[n * OUTW + half * 64 + tid];
    __syncthreads();
    const float* src = x   + (size_t)nc * (Ww * Hh);
    float*       dst = out + (size_t)nc * (OUTW * Hh) + (size_t)half * 64 * Hh;
    #pragma unroll 8
    for (int i = tid; i < 64 * (Hh / 4); i += 256) {
        const int j = ((i >> 7) + rot) & 63;  // rotated output slot
        const int f = i & 127;                // float4 within row
        const fx4 v = __builtin_nontemporal_load(
            reinterpret_cast<const fx4*>(src + (size_t)sidx[j] * Hh + f * 4));
        __builtin_nontemporal_store(v,
            reinterpret_cast<fx4*>(dst + (size_t)j * Hh + f * 4));
    }
}

// ---------------------------------------------------------------------------
extern "C" void kernel_launch(void* const* d_in, const int* in_sizes, int n_in,
                              void* d_out, int out_size, void* d_ws, size_t ws_size,
                              hipStream_t stream) {
    const float* x     = (const float*)d_in[0];
    const float* w1    = (const float*)d_in[1];
    const float* b1    = (const float*)d_in[2];
    const float* gamma = (const float*)d_in[3];
    const float* beta  = (const float*)d_in[4];
    const float* w2    = (const float*)d_in[5];
    const float* b2    = (const float*)d_in[6];
    float* out = (float*)d_out;

    float* pooled = (float*)d_ws;                                    // 32 KB
    float* hbn    = (float*)((char*)d_ws + 32768);                   //  4 KB
    int*   idx    = (int*)((char*)d_ws + 32768 + 4096);              //  8 KB

    pool_kernel<<<Nn * (Ww / 4), 256, 0, stream>>>(x, pooled);
    mlp_h_kernel<<<RED, 256, 0, stream>>>(pooled, w1, b1, gamma, beta, hbn);
    logits_topk_kernel<<<Nn, 512, 0, stream>>>(hbn, w2, b2, idx);
    gather_kernel<<<Nn * Cc * 2, 256, 0, stream>>>(x, idx, out);
}

// Round 13
// 282.256 us; speedup vs baseline: 1.0923x; 1.0923x over previous
//
#include <hip/hip_runtime.h>
#include <cstdint>
#include <math.h>

#define Nn   16
#define Cc   64
#define Ww   512
#define Hh   512
#define RED  64
#define OUTW 128

// Native vector type accepted by __builtin_nontemporal_load/store
typedef float fx4 __attribute__((ext_vector_type(4)));

// ---------------------------------------------------------------------------
// Kernel 1: pooled[n][w] = max over (c,h) of x[n][c][w][h]
// Block b = (n, w-quad): 4 waves, wave r owns row w = q*4+r (2KB/row/c).
// FIX vs R10: per-instruction FULL coalescing — lane reads float4 at
// lane*16B (dense 1KB segment) and at 1KB+lane*16B (second segment), instead
// of the 32B-strided 16B loads (50% line utilization) used before.
// Depth-2 software pipeline; 8 independent accumulators; NT loads.
// ---------------------------------------------------------------------------
__global__ void __launch_bounds__(256) pool_kernel(const float* __restrict__ x,
                                                   float* __restrict__ pooled) {
    const int b = blockIdx.x;            // n*128 + q
    const int n = b >> 7;
    const int q = b & 127;
    const int r = threadIdx.x >> 6;
    const int lane = threadIdx.x & 63;
    const int w = q * 4 + r;
    const float* base = x + ((size_t)n * Cc * Ww + w) * Hh + lane * 4;  // dense
    const size_t cstride = (size_t)Ww * Hh;
    const int HALF = 256;                // floats; 64 lanes x 4 floats = 256

    float m0 = -INFINITY, m1 = -INFINITY, m2 = -INFINITY, m3 = -INFINITY;
    float m4 = -INFINITY, m5 = -INFINITY, m6 = -INFINITY, m7 = -INFINITY;

    fx4 a0 = __builtin_nontemporal_load(reinterpret_cast<const fx4*>(base));
    fx4 a1 = __builtin_nontemporal_load(reinterpret_cast<const fx4*>(base + HALF));
    fx4 b0 = __builtin_nontemporal_load(reinterpret_cast<const fx4*>(base + cstride));
    fx4 b1 = __builtin_nontemporal_load(reinterpret_cast<const fx4*>(base + cstride + HALF));

    #pragma unroll 8
    for (int c = 0; c < Cc - 2; c += 2) {
        const float* p2 = base + (size_t)(c + 2) * cstride;
        const float* p3 = base + (size_t)(c + 3) * cstride;
        const fx4 n0 = __builtin_nontemporal_load(reinterpret_cast<const fx4*>(p2));
        const fx4 n1 = __builtin_nontemporal_load(reinterpret_cast<const fx4*>(p2 + HALF));
        const fx4 n2 = __builtin_nontemporal_load(reinterpret_cast<const fx4*>(p3));
        const fx4 n3 = __builtin_nontemporal_load(reinterpret_cast<const fx4*>(p3 + HALF));
        m0 = fmaxf(m0, a0.x); m1 = fmaxf(m1, a0.y);
        m2 = fmaxf(m2, a0.z); m3 = fmaxf(m3, a0.w);
        m4 = fmaxf(m4, a1.x); m5 = fmaxf(m5, a1.y);
        m6 = fmaxf(m6, a1.z); m7 = fmaxf(m7, a1.w);
        m0 = fmaxf(m0, b0.x); m1 = fmaxf(m1, b0.y);
        m2 = fmaxf(m2, b0.z); m3 = fmaxf(m3, b0.w);
        m4 = fmaxf(m4, b1.x); m5 = fmaxf(m5, b1.y);
        m6 = fmaxf(m6, b1.z); m7 = fmaxf(m7, b1.w);
        a0 = n0; a1 = n1; b0 = n2; b1 = n3;
    }
    m0 = fmaxf(m0, a0.x); m1 = fmaxf(m1, a0.y);
    m2 = fmaxf(m2, a0.z); m3 = fmaxf(m3, a0.w);
    m4 = fmaxf(m4, a1.x); m5 = fmaxf(m5, a1.y);
    m6 = fmaxf(m6, a1.z); m7 = fmaxf(m7, a1.w);
    m0 = fmaxf(m0, b0.x); m1 = fmaxf(m1, b0.y);
    m2 = fmaxf(m2, b0.z); m3 = fmaxf(m3, b0.w);
    m4 = fmaxf(m4, b1.x); m5 = fmaxf(m5, b1.y);
    m6 = fmaxf(m6, b1.z); m7 = fmaxf(m7, b1.w);

    float m = fmaxf(fmaxf(fmaxf(m0, m1), fmaxf(m2, m3)),
                    fmaxf(fmaxf(m4, m5), fmaxf(m6, m7)));
    #pragma unroll
    for (int off = 1; off < 64; off <<= 1)
        m = fmaxf(m, __shfl_xor(m, off, 64));
    if (lane == 0) pooled[n * Ww + w] = m;
}

// ---------------------------------------------------------------------------
// Kernel 2a: h = pooled @ w1.T + b1, BatchNorm(batch stats) + ReLU. (R4)
// ---------------------------------------------------------------------------
__global__ void __launch_bounds__(256) mlp_h_kernel(
    const float* __restrict__ pooled,   // [16][512]
    const float* __restrict__ w1,       // [64][512]
    const float* __restrict__ b1,
    const float* __restrict__ gamma,
    const float* __restrict__ beta,
    float* __restrict__ hbn)            // [64][16]
{
    const int r = blockIdx.x;
    const int t = threadIdx.x;
    const int n = t & 15;
    const int slice = t >> 4;
    const float4* w1r = reinterpret_cast<const float4*>(w1 + r * Ww + slice * 32);
    const float4* pn  = reinterpret_cast<const float4*>(pooled + n * Ww + slice * 32);

    float acc = 0.f;
    #pragma unroll
    for (int j = 0; j < 8; ++j) {
        const float4 a = w1r[j];
        const float4 p = pn[j];
        acc += a.x * p.x + a.y * p.y + a.z * p.z + a.w * p.w;
    }
    __shared__ float part[16][17];
    part[slice][n] = acc;
    __syncthreads();
    if (t < 16) {                        // t == n
        float h = b1[r];
        #pragma unroll
        for (int s = 0; s < 16; ++s) h += part[s][t];
        float sum = h, sq = h * h;
        #pragma unroll
        for (int off = 1; off < 16; off <<= 1) {
            sum += __shfl_xor(sum, off, 64);
            sq  += __shfl_xor(sq,  off, 64);
        }
        const float mu  = sum * (1.f / 16.f);
        const float var = sq  * (1.f / 16.f) - mu * mu;
        const float is  = 1.f / sqrtf(var + 1e-5f);
        const float v   = gamma[r] * (h - mu) * is + beta[r];
        hbn[r * Nn + t] = fmaxf(v, 0.f);
    }
}

// ---------------------------------------------------------------------------
// Kernel 2b: logits + rank-based top-128 (softmax monotone, skipped). (R4)
// Tie-break matches jax.lax.top_k (value desc, index asc); rank-select emits
// indices already sorted ascending.
// ---------------------------------------------------------------------------
__global__ void __launch_bounds__(512) logits_topk_kernel(
    const float* __restrict__ hbn,      // [64][16]
    const float* __restrict__ w2,       // [512][64]
    const float* __restrict__ b2,
    int* __restrict__ idx_out)          // [16][128]
{
    const int row = blockIdx.x;
    const int w = threadIdx.x;

    __shared__ float hrow[RED];
    __shared__ float logits_row[Ww];
    __shared__ unsigned long long sel_mask[Ww / 64];

    float4 wv[16];
    const float4* w2r = reinterpret_cast<const float4*>(w2 + w * RED);
    #pragma unroll
    for (int j = 0; j < 16; ++j) wv[j] = w2r[j];
    if (w < RED) hrow[w] = hbn[w * Nn + row];
    __syncthreads();

    float acc = b2[w];
    #pragma unroll
    for (int j = 0; j < 16; ++j) {
        acc += wv[j].x * hrow[j * 4]     + wv[j].y * hrow[j * 4 + 1]
             + wv[j].z * hrow[j * 4 + 2] + wv[j].w * hrow[j * 4 + 3];
    }
    logits_row[w] = acc;
    __syncthreads();

    const float v = logits_row[w];
    int rank = 0;
    for (int ww = 0; ww < Ww; ++ww) {
        const float u = logits_row[ww];
        rank += (u > v || (u == v && ww < w)) ? 1 : 0;
    }
    const bool sel = (rank < OUTW);
    const unsigned long long m = __ballot(sel);
    if ((w & 63) == 0) sel_mask[w >> 6] = m;
    __syncthreads();
    if (sel) {
        int pos = 0;
        #pragma unroll
        for (int bb = 0; bb < (Ww / 64); ++bb)
            if (bb < (w >> 6)) pos += __popcll(sel_mask[bb]);
        pos += __popcll(sel_mask[w >> 6] & ((1ULL << (w & 63)) - 1ULL));
        idx_out[row * OUTW + pos] = w;
    }
}

// ---------------------------------------------------------------------------
// Kernel 3: gather (R10, rotation reverted). Block b=(n,c,half): 64 sorted
// rows from one 1MB plane into a contiguous 128KB write slab, NT load+store.
// ---------------------------------------------------------------------------
__global__ void __launch_bounds__(256) gather_kernel(const float* __restrict__ x,
                                                     const int* __restrict__ idx,
                                                     float* __restrict__ out) {
    const int b = blockIdx.x;                 // (n*64 + c)*2 + half
    const int half = b & 1;
    const int nc = b >> 1;                    // n*64 + c
    const int n = nc >> 6;
    const int tid = threadIdx.x;
    __shared__ int sidx[64];
    if (tid < 64) sidx[tid] = idx[n * OUTW + half * 64 + tid];
    __syncthreads();
    const float* src = x   + (size_t)nc * (Ww * Hh);
    float*       dst = out + (size_t)nc * (OUTW * Hh) + (size_t)half * 64 * Hh;
    #pragma unroll 8
    for (int i = tid; i < 64 * (Hh / 4); i += 256) {
        const int j = i >> 7;                 // 0..63 local output slot
        const int f = i & 127;                // float4 within row
        const fx4 v = __builtin_nontemporal_load(
            reinterpret_cast<const fx4*>(src + (size_t)sidx[j] * Hh + f * 4));
        __builtin_nontemporal_store(v,
            reinterpret_cast<fx4*>(dst + (size_t)j * Hh + f * 4));
    }
}

// ---------------------------------------------------------------------------
extern "C" void kernel_launch(void* const* d_in, const int* in_sizes, int n_in,
                              void* d_out, int out_size, void* d_ws, size_t ws_size,
                              hipStream_t stream) {
    const float* x     = (const float*)d_in[0];
    const float* w1    = (const float*)d_in[1];
    const float* b1    = (const float*)d_in[2];
    const float* gamma = (const float*)d_in[3];
    const float* beta  = (const float*)d_in[4];
    const float* w2    = (const float*)d_in[5];
    const float* b2    = (const float*)d_in[6];
    float* out = (float*)d_out;

    float* pooled = (float*)d_ws;                                    // 32 KB
    float* hbn    = (float*)((char*)d_ws + 32768);                   //  4 KB
    int*   idx    = (int*)((char*)d_ws + 32768 + 4096);              //  8 KB

    pool_kernel<<<Nn * (Ww / 4), 256, 0, stream>>>(x, pooled);
    mlp_h_kernel<<<RED, 256, 0, stream>>>(pooled, w1, b1, gamma, beta, hbn);
    logits_topk_kernel<<<Nn, 512, 0, stream>>>(hbn, w2, b2, idx);
    gather_kernel<<<Nn * Cc * 2, 256, 0, stream>>>(x, idx, out);
}